// Round 6
// baseline (170.192 us; speedup 1.0000x reference)
//
#include <hip/hip_runtime.h>
#include <hip/hip_bf16.h>

// Problem constants (QREncoder: path signature depth 4 + linear head)
#define BATCH 64
#define LSEQ 256
#define CIN 7
#define CC 8           // channels incl. time
#define NSIG 4680      // 8 + 64 + 512 + 4096
#define KPAD 4736      // NSIG padded to multiple of 64
#define TSTEPS 255     // LSEQ - 1
#define ODIM 512
#define NCHUNK 16      // time chunks for sig write parallelism
#define CH 16          // steps per chunk (last chunk: 15)
#define NKT 74         // KPAD / 64 K-steps

typedef __attribute__((ext_vector_type(8))) unsigned short ushort8;
typedef __attribute__((ext_vector_type(8))) __bf16 bf16x8;
typedef __attribute__((ext_vector_type(4))) float f32x4;

__device__ __forceinline__ unsigned short f2bf(float x) {
    __hip_bfloat16 h = __float2bfloat16(x);   // RNE
    return *(unsigned short*)&h;
}

#define GLDS16(gp, lp)                                                      \
    __builtin_amdgcn_global_load_lds(                                       \
        (const __attribute__((address_space(1))) void*)(gp),                \
        (__attribute__((address_space(3))) void*)(lp), 16, 0, 0)

// ---------------------------------------------------------------------------
// Scan pass A: one block per batch, sequential 255-step state-only scan,
// dumping full state (4680 f32) at t = 16,32,...,240 (15 checkpoints).
// Thread tid carries a1[i1], a2[i1,i2], a3[tid], a4[8t..8t+8) in registers;
// zero cross-thread communication (all increments derive from broadcast dx).
// ---------------------------------------------------------------------------
__global__ __launch_bounds__(512) void sig_ckpt_kernel(const float* __restrict__ inp,
                                                       float* __restrict__ ckpt) {
    __shared__ float sDx[TSTEPS * CC];

    const int b   = blockIdx.x;
    const int tid = threadIdx.x;

    const float* ip = inp + (size_t)b * LSEQ * CIN;
    for (int i = tid; i < TSTEPS * CC; i += 512) {
        int t = i >> 3, c = i & 7;
        sDx[i] = (c == 0) ? (1.0f / 255.0f)
                          : ip[(t + 1) * CIN + (c - 1)] - ip[t * CIN + (c - 1)];
    }
    __syncthreads();

    const int i1 = tid >> 6;
    const int i2 = (tid >> 3) & 7;
    const int i3 = tid & 7;

    float a1own = 0.0f, a2own = 0.0f, a3 = 0.0f;
    float a4[8];
#pragma unroll
    for (int e = 0; e < 8; ++e) a4[e] = 0.0f;

    for (int t = 0; t < 240; ++t) {
        const float* v = &sDx[t * CC];
        const float4 vlo = *(const float4*)&v[0];
        const float4 vhi = *(const float4*)&v[4];
        const float va = v[i1], vb = v[i2], vc = v[i3];
        const float e3s = va * vb * vc * (1.0f / 6.0f);
        const float T4 = e3s * 0.25f + a1own * vb * vc * (1.0f / 6.0f)
                       + a2own * vc * 0.5f + a3;
        a4[0] += vlo.x * T4; a4[1] += vlo.y * T4;
        a4[2] += vlo.z * T4; a4[3] += vlo.w * T4;
        a4[4] += vhi.x * T4; a4[5] += vhi.y * T4;
        a4[6] += vhi.z * T4; a4[7] += vhi.w * T4;
        a3 += e3s + (a1own * vb * 0.5f + a2own) * vc;
        a2own += vb * (0.5f * va + a1own);
        a1own += va;

        if (((t + 1) & 15) == 0) {            // t+1 in {16,...,240}
            const int c = ((t + 1) >> 4) - 1; // 0..14
            float* cp = ckpt + ((size_t)b * 15 + c) * NSIG;
            if ((tid & 63) == 0) cp[i1] = a1own;
            if ((tid & 7) == 0) cp[8 + (tid >> 3)] = a2own;
            cp[72 + tid] = a3;
            float4 q0 = {a4[0], a4[1], a4[2], a4[3]};
            float4 q1 = {a4[4], a4[5], a4[6], a4[7]};
            *(float4*)&cp[584 + tid * 8]     = q0;
            *(float4*)&cp[584 + tid * 8 + 4] = q1;
        }
    }
}

// ---------------------------------------------------------------------------
// Scan pass B: grid (NCHUNK, nb). Block (chunk,b) loads the chunk's start
// state from ckpt (chunk 0: zeros), runs <=16 steps, writes sig rows (bf16).
// ---------------------------------------------------------------------------
__global__ __launch_bounds__(512) void sig_write_kernel(const float* __restrict__ inp,
                                                        const float* __restrict__ ckpt,
                                                        unsigned short* __restrict__ sig) {
    __shared__ float sDx[CH * CC];

    const int chunk = blockIdx.x;
    const int b     = blockIdx.y;
    const int tid   = threadIdx.x;
    const int t0    = chunk * CH;
    const int t1    = (chunk == NCHUNK - 1) ? TSTEPS : t0 + CH;

    const float* ip = inp + (size_t)b * LSEQ * CIN;
    for (int i = tid; i < (t1 - t0) * CC; i += 512) {
        int t = t0 + (i >> 3), c = i & 7;
        sDx[i] = (c == 0) ? (1.0f / 255.0f)
                          : ip[(t + 1) * CIN + (c - 1)] - ip[t * CIN + (c - 1)];
    }
    __syncthreads();

    const int i1 = tid >> 6;
    const int i2 = (tid >> 3) & 7;
    const int i3 = tid & 7;

    float a1own, a2own, a3;
    float a4[8];
    if (chunk == 0) {
        a1own = a2own = a3 = 0.0f;
#pragma unroll
        for (int e = 0; e < 8; ++e) a4[e] = 0.0f;
    } else {
        const float* cp = ckpt + ((size_t)b * 15 + (chunk - 1)) * NSIG;
        a1own = cp[i1];
        a2own = cp[8 + (tid >> 3)];
        a3    = cp[72 + tid];
        float4 q0 = *(const float4*)&cp[584 + tid * 8];
        float4 q1 = *(const float4*)&cp[584 + tid * 8 + 4];
        a4[0] = q0.x; a4[1] = q0.y; a4[2] = q0.z; a4[3] = q0.w;
        a4[4] = q1.x; a4[5] = q1.y; a4[6] = q1.z; a4[7] = q1.w;
    }

    for (int t = t0; t < t1; ++t) {
        const float* v = &sDx[(t - t0) * CC];
        const float4 vlo = *(const float4*)&v[0];
        const float4 vhi = *(const float4*)&v[4];
        const float va = v[i1], vb = v[i2], vc = v[i3];
        const float e3s = va * vb * vc * (1.0f / 6.0f);
        const float T4 = e3s * 0.25f + a1own * vb * vc * (1.0f / 6.0f)
                       + a2own * vc * 0.5f + a3;
        a4[0] += vlo.x * T4; a4[1] += vlo.y * T4;
        a4[2] += vlo.z * T4; a4[3] += vlo.w * T4;
        a4[4] += vhi.x * T4; a4[5] += vhi.y * T4;
        a4[6] += vhi.z * T4; a4[7] += vhi.w * T4;
        a3 += e3s + (a1own * vb * 0.5f + a2own) * vc;
        a2own += vb * (0.5f * va + a1own);
        a1own += va;

        unsigned short* row = sig + ((size_t)b * TSTEPS + t) * KPAD;
        ushort8 pack;
#pragma unroll
        for (int e = 0; e < 8; ++e) pack[e] = f2bf(a4[e]);
        *(ushort8*)(row + 584 + tid * 8) = pack;                // level 4
        row[72 + tid] = f2bf(a3);                               // level 3
        if ((tid & 63) == 0) row[i1] = f2bf(a1own);             // level 1
        if ((tid & 7) == 0) row[8 + (tid >> 3)] = f2bf(a2own);  // level 2
        if (tid >= 448 && tid < 504) row[4232 + tid] = 0;       // pad
    }
}

// ---------------------------------------------------------------------------
// W fp32 [512][4680] -> bf16 [512][KPAD] (pad zeroed)
// ---------------------------------------------------------------------------
__global__ __launch_bounds__(256) void wcvt_kernel(const float* __restrict__ W,
                                                   unsigned short* __restrict__ Wb) {
    int idx = blockIdx.x * 256 + threadIdx.x;
    if (idx >= ODIM * KPAD) return;
    int n = idx / KPAD, k = idx - n * KPAD;
    Wb[idx] = (k < NSIG) ? f2bf(W[(size_t)n * NSIG + k]) : (unsigned short)0;
}

// ---------------------------------------------------------------------------
// MFMA GEMM. out[m][n] = sum_k A[m][k]*Wb[n][k] + bias[n]
// 128x128 tile, BK=64, 4 waves x (64x64, 4x4 frags of 16x16x32 bf16).
// T2 XOR-swizzle (gload_lds-compatible): linear LDS dest, pre-swizzled
// global 16B-block source, matching XOR on ds_read block index (R5: bank
// conflicts 2.9e7 -> 0).
// T3-minimum 2-phase pipeline (this round): LDS double-buffer; issue next
// K-tile's 8 global_load_lds BEFORE computing the current tile; ONE
// __syncthreads per K-step (its implicit vmcnt(0) drain lands after MFMA
// work has overlapped the load latency, instead of immediately after issue).
// XCD-grouped swizzle as before.
// ---------------------------------------------------------------------------
__global__ __launch_bounds__(256) void gemm_kernel(const unsigned short* __restrict__ A,
                                                   const unsigned short* __restrict__ Wb,
                                                   const float* __restrict__ bias,
                                                   float* __restrict__ out,
                                                   int Mrows) {
    __shared__ unsigned short As[2][128 * 64];   // 2 x 16 KB
    __shared__ unsigned short Bs[2][128 * 64];   // 2 x 16 KB

    const int tid = threadIdx.x;
    int nt, mt;
    if (gridDim.y == 128) {                    // full-size dispatch: swizzle
        const int li = blockIdx.y * 4 + blockIdx.x;
        const int x  = li & 7;                 // XCD (round-robin assumption)
        const int j  = li >> 3;
        mt = x * 16 + (j >> 2);
        nt = j & 3;
    } else {
        nt = blockIdx.x; mt = blockIdx.y;
    }
    const int lane = tid & 63;
    const int wv   = tid >> 6;
    const int wr   = wv >> 1;
    const int wc   = wv & 1;
    const int lr   = lane & 15;
    const int lk   = (lane >> 4) * 8;
    const int sb   = lr & 7;                  // read-side swizzle key

    const f32x4 z4 = {0.0f, 0.0f, 0.0f, 0.0f};
    f32x4 acc[4][4];
#pragma unroll
    for (int i = 0; i < 4; ++i)
#pragma unroll
        for (int j = 0; j < 4; ++j) acc[i][j] = z4;

    const int srow = tid >> 3;                          // 0..31
    const int gcb  = (tid & 7) ^ (srow & 7);            // pre-swizzled src block
    const int scol = gcb * 8;                           // element offset in BK

    // per-lane global source pointers (A row clamped for M-tail)
    const unsigned short* aptr[4];
    const unsigned short* bptr[4];
#pragma unroll
    for (int i = 0; i < 4; ++i) {
        int gr = mt * 128 + i * 32 + srow;
        if (gr >= Mrows) gr = 0;
        aptr[i] = A + (size_t)gr * KPAD + scol;
        bptr[i] = Wb + (size_t)(nt * 128 + i * 32 + srow) * KPAD + scol;
    }

    // prologue: stage K-tile 0 into buffer 0
#pragma unroll
    for (int i = 0; i < 4; ++i) {
        GLDS16(aptr[i], ((char*)As[0]) + i * 4096 + tid * 16);
        GLDS16(bptr[i], ((char*)Bs[0]) + i * 4096 + tid * 16);
    }
    __syncthreads();

    int cur = 0;
    for (int t = 0; t < NKT; ++t) {
        // prefetch next K-tile into the other buffer (overlaps with MFMA below)
        if (t + 1 < NKT) {
            const int koff = (t + 1) * 64;
#pragma unroll
            for (int i = 0; i < 4; ++i) {
                GLDS16(aptr[i] + koff, ((char*)As[cur ^ 1]) + i * 4096 + tid * 16);
                GLDS16(bptr[i] + koff, ((char*)Bs[cur ^ 1]) + i * 4096 + tid * 16);
            }
        }

        const unsigned short* as = As[cur];
        const unsigned short* bs = Bs[cur];
#pragma unroll
        for (int ks = 0; ks < 2; ++ks) {
            const int kb  = (ks * 32 + lk) >> 3;        // 16B-block index 0..7
            const int kel = (kb ^ sb) * 8;              // swizzled element col
            bf16x8 af[4], bf[4];
#pragma unroll
            for (int i = 0; i < 4; ++i)
                af[i] = *(const bf16x8*)&as[(wr * 64 + i * 16 + lr) * 64 + kel];
#pragma unroll
            for (int j = 0; j < 4; ++j)
                bf[j] = *(const bf16x8*)&bs[(wc * 64 + j * 16 + lr) * 64 + kel];
#pragma unroll
            for (int i = 0; i < 4; ++i)
#pragma unroll
                for (int j = 0; j < 4; ++j)
                    acc[i][j] = __builtin_amdgcn_mfma_f32_16x16x32_bf16(
                        af[i], bf[j], acc[i][j], 0, 0, 0);
        }

        // one barrier per K-step: implicit vmcnt(0)+lgkmcnt(0) drain makes the
        // prefetched buffer ready AND protects buf[cur] from next re-stage.
        __syncthreads();
        cur ^= 1;
    }

    float bn[4];
#pragma unroll
    for (int j = 0; j < 4; ++j)
        bn[j] = bias[nt * 128 + wc * 64 + j * 16 + lr];

#pragma unroll
    for (int i = 0; i < 4; ++i) {
        const int mbase = mt * 128 + wr * 64 + i * 16 + (lane >> 4) * 4;
#pragma unroll
        for (int r = 0; r < 4; ++r) {
            const int m = mbase + r;
            if (m < Mrows) {
#pragma unroll
                for (int j = 0; j < 4; ++j) {
                    const int n = nt * 128 + wc * 64 + j * 16 + lr;
                    out[(size_t)m * ODIM + n] = acc[i][j][r] + bn[j];
                }
            }
        }
    }
}

extern "C" void kernel_launch(void* const* d_in, const int* in_sizes, int n_in,
                              void* d_out, int out_size, void* d_ws, size_t ws_size,
                              hipStream_t stream) {
    const float* inp  = (const float*)d_in[0];
    const float* W    = (const float*)d_in[1];
    const float* bias = (const float*)d_in[2];
    float* out = (float*)d_out;

    const size_t wbBytes = (size_t)ODIM * KPAD * sizeof(unsigned short);
    const size_t sigPB   = (size_t)TSTEPS * KPAD * sizeof(unsigned short); // 2.42 MB
    const size_t ckptPB  = (size_t)15 * NSIG * sizeof(float);              // 0.28 MB
    const size_t perB    = sigPB + ckptPB;

    int nbMax = (int)((ws_size - wbBytes) / perB);
    if (nbMax > BATCH) nbMax = BATCH;
    if (nbMax < 1) nbMax = 1;

    unsigned short* sig  = (unsigned short*)d_ws;
    float*          ckpt = (float*)((char*)d_ws + (size_t)nbMax * sigPB);
    unsigned short* Wb   = (unsigned short*)((char*)d_ws + (ws_size - wbBytes));

    wcvt_kernel<<<(ODIM * KPAD + 255) / 256, 256, 0, stream>>>(W, Wb);

    for (int b0 = 0; b0 < BATCH; b0 += nbMax) {
        const int nb = (b0 + nbMax <= BATCH) ? nbMax : (BATCH - b0);
        const int Mrows = nb * TSTEPS;
        const float* ipb = inp + (size_t)b0 * LSEQ * CIN;
        sig_ckpt_kernel<<<nb, 512, 0, stream>>>(ipb, ckpt);
        sig_write_kernel<<<dim3(NCHUNK, nb), 512, 0, stream>>>(ipb, ckpt, sig);
        gemm_kernel<<<dim3(ODIM / 128, (Mrows + 127) / 128), 256, 0, stream>>>(
            sig, Wb, bias, out + (size_t)b0 * TSTEPS * ODIM, Mrows);
    }
}